// Round 12
// baseline (358.071 us; speedup 1.0000x reference)
//
#include <hip/hip_runtime.h>
#include <hip/hip_bf16.h>
#include <math.h>

#define NB 8192
#define NK 4096
#define ND 1024
#define NL 8
#define RES_THR 1e-3f

typedef __bf16 bf16x8 __attribute__((ext_vector_type(8)));
typedef float f32x4 __attribute__((ext_vector_type(4)));

#define MFMA16(a, b, c) __builtin_amdgcn_mfma_f32_16x16x32_bf16(a, b, c, 0, 0, 0)

#define GLOAD(g, l)                                                        \
  __builtin_amdgcn_global_load_lds(                                        \
      (const __attribute__((address_space(1))) void*)(g),                  \
      (__attribute__((address_space(3))) void*)(l), 16, 0, 0)

__device__ __forceinline__ unsigned short f2bf(float x) {
  __hip_bfloat16 h = __float2bfloat16(x);
  return __builtin_bit_cast(unsigned short, h);
}
__device__ __forceinline__ float bf2f(unsigned short u) {
  return __bfloat162float(__builtin_bit_cast(__hip_bfloat16, u));
}

__device__ __forceinline__ float wave_reduce_sum(float v) {
#pragma unroll
  for (int off = 32; off > 0; off >>= 1) v += __shfl_down(v, off);
  return v;
}

__device__ __forceinline__ void top2_merge(float& v1, int& k1, float& v2,
                                           int& k2, float w1, int j1, float w2,
                                           int j2) {
  if (w1 > v1 || (w1 == v1 && j1 < k1)) {
    if (v1 > w2 || (v1 == w2 && k1 < j2)) { v2 = v1; k2 = k1; }
    else { v2 = w2; k2 = j2; }
    v1 = w1; k1 = j1;
  } else {
    if (w1 > v2 || (w1 == v2 && j1 < k2)) { v2 = w1; k2 = j1; }
  }
}

// Prep codebook hi bf16: Bh[NK][ND]
__global__ __launch_bounds__(256) void k_prep(const float* __restrict__ cb,
                                              unsigned short* __restrict__ Bh) {
  int b = blockIdx.x, t = threadIdx.x;
  float4 v = ((const float4*)(cb + (size_t)b * ND))[t];
  ushort4 h;
  h.x = f2bf(v.x); h.y = f2bf(v.y); h.z = f2bf(v.z); h.w = f2bf(v.w);
  ((ushort4*)(Bh + (size_t)b * ND))[t] = h;
}

// Init: residual(f32, in d_out) = targets; Ah = bf16(targets); active flags.
__global__ __launch_bounds__(256) void k_init(const float* __restrict__ tgt,
                                              float* __restrict__ resid,
                                              unsigned short* __restrict__ Ah,
                                              int* __restrict__ active) {
  int b = blockIdx.x, t = threadIdx.x;
  float4 v = ((const float4*)(tgt + (size_t)b * ND))[t];
  ((float4*)(resid + (size_t)b * ND))[t] = v;
  ushort4 h;
  h.x = f2bf(v.x); h.y = f2bf(v.y); h.z = f2bf(v.z); h.w = f2bf(v.w);
  ((ushort4*)(Ah + (size_t)b * ND))[t] = h;
  float ss = v.x * v.x + v.y * v.y + v.z * v.z + v.w * v.w;
  ss = wave_reduce_sum(ss);
  __shared__ float red[4];
  if ((t & 63) == 0) red[t >> 6] = ss;
  __syncthreads();
  if (t == 0) {
    float tot = red[0] + red[1] + red[2] + red[3];
    active[b] = (sqrtf(tot) >= RES_THR) ? 1 : 0;
  }
}

// 256x256-tile bf16 GEMM core (8 waves, BK=64, dbuf LDS, counted vmcnt).
// Writes optional bf16 score tile (sc) and optional per-row top-2 (part).
__global__ __launch_bounds__(512) void k_score0(
    const unsigned short* __restrict__ Ah, const unsigned short* __restrict__ Bh,
    float4* __restrict__ part, unsigned short* __restrict__ sc) {
  __shared__ __align__(16) char sA0[32768];
  __shared__ __align__(16) char sA1[32768];
  __shared__ __align__(16) char sB0[32768];
  __shared__ __align__(16) char sB1[32768];
  const int tid = threadIdx.x;
  const int lane = tid & 63;
  const int swzid = (blockIdx.x & 7) * 64 + (blockIdx.x >> 3);
  const int bm = swzid >> 4;
  const int bn = swzid & 15;
  const int wid = tid >> 6;
  const int wr = wid >> 2;
  const int wc = wid & 3;

  const int srow = tid >> 3;
  const int sblk = (tid & 7) ^ (srow & 7);
  const unsigned short* aSrc = Ah + (size_t)(bm * 256 + srow) * ND + sblk * 8;
  const unsigned short* bSrc = Bh + (size_t)(bn * 256 + srow) * ND + sblk * 8;

  const int lr = lane & 15;
  const int lk = lane >> 4;
  const int swz = lr & 7;
  const int kb0 = ((lk ^ swz) << 4);
  const int kb1 = (((4 + lk) ^ swz) << 4);

  f32x4 acc[8][4];
#pragma unroll
  for (int m = 0; m < 8; ++m)
#pragma unroll
    for (int n = 0; n < 4; ++n) acc[m][n] = (f32x4)(0.f);

#pragma unroll
  for (int rr = 0; rr < 4; ++rr) {
    GLOAD(aSrc + (size_t)(rr * 64) * ND, sA0 + rr * 8192 + tid * 16);
    GLOAD(bSrc + (size_t)(rr * 64) * ND, sB0 + rr * 8192 + tid * 16);
  }
#pragma unroll
  for (int rr = 0; rr < 4; ++rr) {
    GLOAD(aSrc + (size_t)(rr * 64) * ND + 64, sA1 + rr * 8192 + tid * 16);
    GLOAD(bSrc + (size_t)(rr * 64) * ND + 64, sB1 + rr * 8192 + tid * 16);
  }

#pragma unroll 1
  for (int kt = 0; kt < 16; ++kt) {
    const char* pa = (kt & 1) ? sA1 : sA0;
    const char* pb = (kt & 1) ? sB1 : sB0;
    if (kt < 15) {
      asm volatile("s_waitcnt vmcnt(8)" ::: "memory");
    } else {
      asm volatile("s_waitcnt vmcnt(0)" ::: "memory");
    }
    __builtin_amdgcn_s_barrier();
    bf16x8 af0[8], bf0[4];
#pragma unroll
    for (int m = 0; m < 8; ++m)
      af0[m] = *(const bf16x8*)(pa + (wr * 128 + m * 16 + lr) * 128 + kb0);
#pragma unroll
    for (int n = 0; n < 4; ++n)
      bf0[n] = *(const bf16x8*)(pb + (wc * 64 + n * 16 + lr) * 128 + kb0);
    __builtin_amdgcn_s_setprio(1);
#pragma unroll
    for (int m = 0; m < 8; ++m)
#pragma unroll
      for (int n = 0; n < 4; ++n) acc[m][n] = MFMA16(af0[m], bf0[n], acc[m][n]);
    __builtin_amdgcn_s_setprio(0);
    bf16x8 af1[8], bf1[4];
#pragma unroll
    for (int m = 0; m < 8; ++m)
      af1[m] = *(const bf16x8*)(pa + (wr * 128 + m * 16 + lr) * 128 + kb1);
#pragma unroll
    for (int n = 0; n < 4; ++n)
      bf1[n] = *(const bf16x8*)(pb + (wc * 64 + n * 16 + lr) * 128 + kb1);
    __syncthreads();  // all waves done reading buf[kt&1]
    if (kt < 14) {
      const int k0 = (kt + 2) << 6;
      char* da = (kt & 1) ? sA1 : sA0;
      char* db = (kt & 1) ? sB1 : sB0;
#pragma unroll
      for (int rr = 0; rr < 4; ++rr) {
        GLOAD(aSrc + (size_t)(rr * 64) * ND + k0, da + rr * 8192 + tid * 16);
        GLOAD(bSrc + (size_t)(rr * 64) * ND + k0, db + rr * 8192 + tid * 16);
      }
    }
    __builtin_amdgcn_s_setprio(1);
#pragma unroll
    for (int m = 0; m < 8; ++m)
#pragma unroll
      for (int n = 0; n < 4; ++n) acc[m][n] = MFMA16(af1[m], bf1[n], acc[m][n]);
    __builtin_amdgcn_s_setprio(0);
  }
  __syncthreads();

  // optional bf16 scores store
  if (sc) {
#pragma unroll
    for (int m = 0; m < 8; ++m) {
      int row = bm * 256 + wr * 128 + m * 16 + lk * 4;
#pragma unroll
      for (int q = 0; q < 4; ++q)
#pragma unroll
        for (int n = 0; n < 4; ++n)
          sc[(size_t)(row + q) * NK + bn * 256 + wc * 64 + n * 16 + lr] =
              f2bf(acc[m][n][q]);
    }
  }

  // optional fused top-2 per row (fallback path only)
  if (part) {
    float4* red = (float4*)sA0;
#pragma unroll
    for (int m = 0; m < 8; ++m) {
#pragma unroll
      for (int q = 0; q < 4; ++q) {
        float v1 = acc[m][0][q];
        int k1 = bn * 256 + wc * 64 + lr;
        float v2 = -INFINITY;
        int k2 = 0x7fffffff;
#pragma unroll
        for (int n = 1; n < 4; ++n) {
          top2_merge(v1, k1, v2, k2, acc[m][n][q],
                     bn * 256 + wc * 64 + n * 16 + lr, -INFINITY, 0x7fffffff);
        }
#pragma unroll
        for (int msk = 1; msk < 16; msk <<= 1) {
          float ov1 = __shfl_xor(v1, msk);
          int ok1 = __shfl_xor(k1, msk);
          float ov2 = __shfl_xor(v2, msk);
          int ok2 = __shfl_xor(k2, msk);
          top2_merge(v1, k1, v2, k2, ov1, ok1, ov2, ok2);
        }
        if (lr == 0) {
          int row = wr * 128 + m * 16 + lk * 4 + q;
          red[row * 4 + wc] =
              make_float4(v1, __int_as_float(k1), v2, __int_as_float(k2));
        }
      }
    }
    __syncthreads();
    if (tid < 256) {
      float4 e0 = red[tid * 4 + 0];
      float v1 = e0.x; int k1 = __float_as_int(e0.y);
      float v2 = e0.z; int k2 = __float_as_int(e0.w);
#pragma unroll
      for (int j = 1; j < 4; ++j) {
        float4 e = red[tid * 4 + j];
        top2_merge(v1, k1, v2, k2, e.x, __float_as_int(e.y), e.z,
                   __float_as_int(e.w));
      }
      part[(size_t)(bm * 256 + tid) * 16 + bn] =
          make_float4(v1, __int_as_float(k1), v2, __int_as_float(k2));
    }
  }
}

// Gram: G[i][j] = bf16(cb_i) . bf16(cb_j), bf16 out. Same GEMM core, 16x16 grid.
__global__ __launch_bounds__(512) void k_gram(const unsigned short* __restrict__ Bh,
                                              unsigned short* __restrict__ G) {
  __shared__ __align__(16) char sA0[32768];
  __shared__ __align__(16) char sA1[32768];
  __shared__ __align__(16) char sB0[32768];
  __shared__ __align__(16) char sB1[32768];
  const int tid = threadIdx.x;
  const int lane = tid & 63;
  const int bm = blockIdx.x >> 4;
  const int bn = blockIdx.x & 15;
  const int wid = tid >> 6;
  const int wr = wid >> 2;
  const int wc = wid & 3;
  const int srow = tid >> 3;
  const int sblk = (tid & 7) ^ (srow & 7);
  const unsigned short* aSrc = Bh + (size_t)(bm * 256 + srow) * ND + sblk * 8;
  const unsigned short* bSrc = Bh + (size_t)(bn * 256 + srow) * ND + sblk * 8;
  const int lr = lane & 15;
  const int lk = lane >> 4;
  const int swz = lr & 7;
  const int kb0 = ((lk ^ swz) << 4);
  const int kb1 = (((4 + lk) ^ swz) << 4);

  f32x4 acc[8][4];
#pragma unroll
  for (int m = 0; m < 8; ++m)
#pragma unroll
    for (int n = 0; n < 4; ++n) acc[m][n] = (f32x4)(0.f);

#pragma unroll
  for (int rr = 0; rr < 4; ++rr) {
    GLOAD(aSrc + (size_t)(rr * 64) * ND, sA0 + rr * 8192 + tid * 16);
    GLOAD(bSrc + (size_t)(rr * 64) * ND, sB0 + rr * 8192 + tid * 16);
  }
#pragma unroll
  for (int rr = 0; rr < 4; ++rr) {
    GLOAD(aSrc + (size_t)(rr * 64) * ND + 64, sA1 + rr * 8192 + tid * 16);
    GLOAD(bSrc + (size_t)(rr * 64) * ND + 64, sB1 + rr * 8192 + tid * 16);
  }
#pragma unroll 1
  for (int kt = 0; kt < 16; ++kt) {
    const char* pa = (kt & 1) ? sA1 : sA0;
    const char* pb = (kt & 1) ? sB1 : sB0;
    if (kt < 15) {
      asm volatile("s_waitcnt vmcnt(8)" ::: "memory");
    } else {
      asm volatile("s_waitcnt vmcnt(0)" ::: "memory");
    }
    __builtin_amdgcn_s_barrier();
    bf16x8 af0[8], bf0[4];
#pragma unroll
    for (int m = 0; m < 8; ++m)
      af0[m] = *(const bf16x8*)(pa + (wr * 128 + m * 16 + lr) * 128 + kb0);
#pragma unroll
    for (int n = 0; n < 4; ++n)
      bf0[n] = *(const bf16x8*)(pb + (wc * 64 + n * 16 + lr) * 128 + kb0);
    __builtin_amdgcn_s_setprio(1);
#pragma unroll
    for (int m = 0; m < 8; ++m)
#pragma unroll
      for (int n = 0; n < 4; ++n) acc[m][n] = MFMA16(af0[m], bf0[n], acc[m][n]);
    __builtin_amdgcn_s_setprio(0);
    bf16x8 af1[8], bf1[4];
#pragma unroll
    for (int m = 0; m < 8; ++m)
      af1[m] = *(const bf16x8*)(pa + (wr * 128 + m * 16 + lr) * 128 + kb1);
#pragma unroll
    for (int n = 0; n < 4; ++n)
      bf1[n] = *(const bf16x8*)(pb + (wc * 64 + n * 16 + lr) * 128 + kb1);
    __syncthreads();
    if (kt < 14) {
      const int k0 = (kt + 2) << 6;
      char* da = (kt & 1) ? sA1 : sA0;
      char* db = (kt & 1) ? sB1 : sB0;
#pragma unroll
      for (int rr = 0; rr < 4; ++rr) {
        GLOAD(aSrc + (size_t)(rr * 64) * ND + k0, da + rr * 8192 + tid * 16);
        GLOAD(bSrc + (size_t)(rr * 64) * ND + k0, db + rr * 8192 + tid * 16);
      }
    }
    __builtin_amdgcn_s_setprio(1);
#pragma unroll
    for (int m = 0; m < 8; ++m)
#pragma unroll
      for (int n = 0; n < 4; ++n) acc[m][n] = MFMA16(af1[m], bf1[n], acc[m][n]);
    __builtin_amdgcn_s_setprio(0);
  }
#pragma unroll
  for (int m = 0; m < 8; ++m) {
    int row = bm * 256 + wr * 128 + m * 16 + lk * 4;
#pragma unroll
    for (int q = 0; q < 4; ++q)
#pragma unroll
      for (int n = 0; n < 4; ++n)
        G[(size_t)(row + q) * NK + bn * 256 + wc * 64 + n * 16 + lr] =
            f2bf(acc[m][n][q]);
  }
}

// Fused full loop, one block per row. Scores in f32 registers across steps.
// Per step: max -> margin candidates (+speculative argmax gathers of cb/G
// rows) -> cnt==1 fast path (provably exact) else serial exact rescore ->
// residual + reg-scores update.
__global__ __launch_bounds__(256, 8) void k_all(
    const unsigned short* __restrict__ sc0, const unsigned short* __restrict__ G,
    const float* __restrict__ cb, float* __restrict__ resid,
    float* __restrict__ out_idx, const int* __restrict__ active0) {
  const int b = blockIdx.x, t = threadIdx.x;
  __shared__ float s_max[4];
  __shared__ float s_nrm[4];
  __shared__ float s_red[4];
  __shared__ int s_cnt;
  __shared__ int s_spec;
  __shared__ int s_k[64];
  __shared__ float s_bv;
  __shared__ int s_bk;

  float4 r = ((const float4*)(resid + (size_t)b * ND))[t];

  float scv[16];
  {
    const unsigned short* srow = sc0 + (size_t)b * NK;
    uint4 v0 = *(const uint4*)(srow + t * 8);
    uint4 v1 = *(const uint4*)(srow + 2048 + t * 8);
    unsigned w[8] = {v0.x, v0.y, v0.z, v0.w, v1.x, v1.y, v1.z, v1.w};
#pragma unroll
    for (int j = 0; j < 8; ++j) {
      scv[2 * j] = bf2f((unsigned short)(w[j] & 0xffff));
      scv[2 * j + 1] = bf2f((unsigned short)(w[j] >> 16));
    }
  }
  int act = active0[b];
  float decay = 1.0f;

#pragma unroll 1
  for (int s = 0; s < NL; ++s) {
    // phase 1: block max of scores + residual norm (fused shuffle reduce)
    float m = scv[0];
#pragma unroll
    for (int i = 1; i < 16; ++i) m = fmaxf(m, scv[i]);
    float ss = r.x * r.x + r.y * r.y + r.z * r.z + r.w * r.w;
#pragma unroll
    for (int off = 32; off > 0; off >>= 1) {
      m = fmaxf(m, __shfl_xor(m, off));
      ss += __shfl_xor(ss, off);
    }
    if ((t & 63) == 0) { s_max[t >> 6] = m; s_nrm[t >> 6] = ss; }
    if (t == 0) {
      s_cnt = 0;
      s_spec = 0x7fffffff;
      s_bv = -INFINITY;
      s_bk = 0x7fffffff;
    }
    __syncthreads();
    const float M = fmaxf(fmaxf(s_max[0], s_max[1]), fmaxf(s_max[2], s_max[3]));
    const float nrm = s_nrm[0] + s_nrm[1] + s_nrm[2] + s_nrm[3];
    act = (act && sqrtf(nrm) >= RES_THR) ? 1 : 0;
    const float margin = (s == 0) ? 2.5f : 6.0f;
    // phase 2: collect candidates within margin; record approx argmax (spec)
#pragma unroll
    for (int i = 0; i < 16; ++i) {
      if (scv[i] >= M - margin) {
        int col = (i < 8) ? (t * 8 + i) : (2048 + t * 8 + (i - 8));
        int pos = atomicAdd(&s_cnt, 1);
        if (pos < 64) s_k[pos] = col;
        if (scv[i] == M) atomicMin(&s_spec, col);
      }
    }
    __syncthreads();
    const int kspec = s_spec;
    // speculative gathers for the (near-certain) winner: cb row + G row
    float4 cvs = ((const float4*)(cb + (size_t)kspec * ND))[t];
    uint4 g0s = make_uint4(0, 0, 0, 0), g1s = make_uint4(0, 0, 0, 0);
    const bool want_g = (s < NL - 1);
    if (want_g) {
      const unsigned short* gs = G + (size_t)kspec * NK;
      g0s = *(const uint4*)(gs + t * 8);
      g1s = *(const uint4*)(gs + 2048 + t * 8);
    }
    const int cnt = s_cnt < 64 ? s_cnt : 64;
    int kbest;
    if (cnt <= 1) {
      // sole candidate within margin == true argmax (margin >= 2*err bound)
      kbest = kspec;
    } else {
      for (int c = 0; c < cnt; ++c) {
        int k = s_k[c];
        float4 cv = ((const float4*)(cb + (size_t)k * ND))[t];
        float dd = r.x * cv.x + r.y * cv.y + r.z * cv.z + r.w * cv.w;
        dd = wave_reduce_sum(dd);
        if ((t & 63) == 0) s_red[t >> 6] = dd;
        __syncthreads();
        if (t == 0) {
          float scr = s_red[0] + s_red[1] + s_red[2] + s_red[3];
          if (scr > s_bv || (scr == s_bv && k < s_bk)) { s_bv = scr; s_bk = k; }
        }
        __syncthreads();
      }
      kbest = s_bk;
    }
    if (t == 0) out_idx[(size_t)b * NL + s] = act ? (float)kbest : -1.0f;
    if (act) {
      float4 cv = (kbest == kspec)
                      ? cvs
                      : ((const float4*)(cb + (size_t)kbest * ND))[t];
      r.x -= decay * cv.x;
      r.y -= decay * cv.y;
      r.z -= decay * cv.z;
      r.w -= decay * cv.w;
      if (want_g) {
        uint4 G0, G1;
        if (kbest == kspec) {
          G0 = g0s;
          G1 = g1s;
        } else {
          const unsigned short* grow = G + (size_t)kbest * NK;
          G0 = *(const uint4*)(grow + t * 8);
          G1 = *(const uint4*)(grow + 2048 + t * 8);
        }
        unsigned w[8] = {G0.x, G0.y, G0.z, G0.w, G1.x, G1.y, G1.z, G1.w};
#pragma unroll
        for (int j = 0; j < 8; ++j) {
          scv[2 * j] -= decay * bf2f((unsigned short)(w[j] & 0xffff));
          scv[2 * j + 1] -= decay * bf2f((unsigned short)(w[j] >> 16));
        }
      }
    }
    decay *= 0.9f;
    __syncthreads();  // protect s_* resets at top of next step
  }
  ((float4*)(resid + (size_t)b * ND))[t] = r;
}

// Merge partials (fallback path only).
__global__ __launch_bounds__(256) void k_update(
    float* __restrict__ resid, const float* __restrict__ cb,
    const float4* __restrict__ part, int* __restrict__ active,
    float* __restrict__ out_idx, unsigned short* __restrict__ Ah, float decay,
    int s, int nseg, float margin) {
  int b = blockIdx.x, t = threadIdx.x;
  __shared__ int s_cnt;
  __shared__ int s_k[32];
  __shared__ float s_red[4];
  __shared__ float s_bv;
  __shared__ int s_bk;

  float4 r = ((const float4*)(resid + (size_t)b * ND))[t];

  if (t < 2 * nseg) {
    float4 e = part[(size_t)b * 16 + (t >> 1)];
    float v = (t & 1) ? e.z : e.x;
    int k = __float_as_int((t & 1) ? e.w : e.y);
    float M = v;
    for (int off = nseg; off > 0; off >>= 1) M = fmaxf(M, __shfl_xor(M, off));
    bool cand = (v >= M - margin);
    unsigned long long mask = __ballot(cand);
    int slot = __popcll(mask & ((1ull << t) - 1ull));
    if (cand && slot < 32) s_k[slot] = k;
    if (t == 0) {
      int n = (int)__popcll(mask);
      s_cnt = n < 32 ? n : 32;
      s_bv = -INFINITY;
      s_bk = 0x7fffffff;
    }
  }
  __syncthreads();
  int cnt = s_cnt;
  for (int c = 0; c < cnt; ++c) {
    int k = s_k[c];
    float4 cv = ((const float4*)(cb + (size_t)k * ND))[t];
    float dd = r.x * cv.x + r.y * cv.y + r.z * cv.z + r.w * cv.w;
    dd = wave_reduce_sum(dd);
    if ((t & 63) == 0) s_red[t >> 6] = dd;
    __syncthreads();
    if (t == 0) {
      float sc = s_red[0] + s_red[1] + s_red[2] + s_red[3];
      if (sc > s_bv || (sc == s_bv && k < s_bk)) { s_bv = sc; s_bk = k; }
    }
    __syncthreads();
  }
  int kbest = s_bk;
  int act = active[b];
  float4 cv = ((const float4*)(cb + (size_t)kbest * ND))[t];
  if (act) {
    r.x -= decay * cv.x;
    r.y -= decay * cv.y;
    r.z -= decay * cv.z;
    r.w -= decay * cv.w;
  }
  ((float4*)(resid + (size_t)b * ND))[t] = r;
  if (Ah) {
    ushort4 h;
    h.x = f2bf(r.x); h.y = f2bf(r.y); h.z = f2bf(r.z); h.w = f2bf(r.w);
    ((ushort4*)(Ah + (size_t)b * ND))[t] = h;
  }
  float ss = r.x * r.x + r.y * r.y + r.z * r.z + r.w * r.w;
  ss = wave_reduce_sum(ss);
  if ((t & 63) == 0) s_red[t >> 6] = ss;
  __syncthreads();
  if (t == 0) {
    float tot = s_red[0] + s_red[1] + s_red[2] + s_red[3];
    out_idx[(size_t)b * NL + s] = act ? (float)kbest : -1.0f;
    active[b] = (act && sqrtf(tot) >= RES_THR) ? 1 : 0;
  }
}

extern "C" void kernel_launch(void* const* d_in, const int* in_sizes, int n_in,
                              void* d_out, int out_size, void* d_ws,
                              size_t ws_size, hipStream_t stream) {
  const float* targets = (const float*)d_in[0];
  const float* codebook = (const float*)d_in[1];
  float* out = (float*)d_out;
  float* out_idx = out;
  float* resid = out + (size_t)NB * NL;

  char* ws = (char*)d_ws;
  const size_t SC_SZ = (size_t)NB * NK * 2;        // 64MB
  const size_t G_SZ = (size_t)NK * NK * 2;         // 32MB
  const size_t AH_SZ = (size_t)NB * ND * 2;        // 16MB
  const size_t BH_SZ = (size_t)NK * ND * 2;        // 8MB
  const size_t PART_SZ = (size_t)NB * 16 * 16;     // 2MB
  const size_t NEED = SC_SZ + G_SZ + AH_SZ + BH_SZ + PART_SZ + 32768;

  if (ws_size >= NEED) {
    // incremental-Gram path, fully fused step loop
    unsigned short* scores = (unsigned short*)ws;
    unsigned short* G = (unsigned short*)(ws + SC_SZ);
    unsigned short* Ah = (unsigned short*)(ws + SC_SZ + G_SZ);
    unsigned short* Bh = (unsigned short*)(ws + SC_SZ + G_SZ + AH_SZ);
    int* active = (int*)(ws + SC_SZ + G_SZ + AH_SZ + BH_SZ + PART_SZ);

    k_prep<<<NK, 256, 0, stream>>>(codebook, Bh);
    k_init<<<NB, 256, 0, stream>>>(targets, resid, Ah, active);
    k_gram<<<256, 512, 0, stream>>>(Bh, G);
    k_score0<<<(NB / 256) * (NK / 256), 512, 0, stream>>>(Ah, Bh, nullptr,
                                                          scores);
    k_all<<<NB, 256, 0, stream>>>(scores, G, codebook, resid, out_idx, active);
  } else {
    // fallback: proven round-8 loop (full GEMM per step)
    float4* part = (float4*)ws;
    int* active = (int*)(ws + PART_SZ);
    unsigned short* Ah = (unsigned short*)(ws + PART_SZ + 65536);
    unsigned short* Bh = Ah + (size_t)NB * ND;

    k_prep<<<NK, 256, 0, stream>>>(codebook, Bh);
    k_init<<<NB, 256, 0, stream>>>(targets, resid, Ah, active);
    for (int s = 0; s < NL; ++s) {
      k_score0<<<(NB / 256) * (NK / 256), 512, 0, stream>>>(Ah, Bh, part,
                                                            nullptr);
      float ds = (float)pow(0.9, (double)s);
      k_update<<<NB, 256, 0, stream>>>(resid, codebook, part, active, out_idx,
                                       Ah, ds, s, 16, 2.5f);
    }
  }
}

// Round 13
// 274.127 us; speedup vs baseline: 1.3062x; 1.3062x over previous
//
#include <hip/hip_runtime.h>
#include <hip/hip_bf16.h>
#include <math.h>

#define NB 8192
#define NK 4096
#define ND 1024
#define NL 8
#define RES_THR 1e-3f

typedef __bf16 bf16x8 __attribute__((ext_vector_type(8)));
typedef float f32x4 __attribute__((ext_vector_type(4)));

#define MFMA16(a, b, c) __builtin_amdgcn_mfma_f32_16x16x32_bf16(a, b, c, 0, 0, 0)

#define GLOAD(g, l)                                                        \
  __builtin_amdgcn_global_load_lds(                                        \
      (const __attribute__((address_space(1))) void*)(g),                  \
      (__attribute__((address_space(3))) void*)(l), 16, 0, 0)

__device__ __forceinline__ unsigned short f2bf(float x) {
  __hip_bfloat16 h = __float2bfloat16(x);
  return __builtin_bit_cast(unsigned short, h);
}
__device__ __forceinline__ float bf2f(unsigned short u) {
  return __bfloat162float(__builtin_bit_cast(__hip_bfloat16, u));
}

__device__ __forceinline__ float wave_reduce_sum(float v) {
#pragma unroll
  for (int off = 32; off > 0; off >>= 1) v += __shfl_down(v, off);
  return v;
}

__device__ __forceinline__ void top2_merge(float& v1, int& k1, float& v2,
                                           int& k2, float w1, int j1, float w2,
                                           int j2) {
  if (w1 > v1 || (w1 == v1 && j1 < k1)) {
    if (v1 > w2 || (v1 == w2 && k1 < j2)) { v2 = v1; k2 = k1; }
    else { v2 = w2; k2 = j2; }
    v1 = w1; k1 = j1;
  } else {
    if (w1 > v2 || (w1 == v2 && j1 < k2)) { v2 = w1; k2 = j1; }
  }
}

// Prep codebook hi bf16: Bh[NK][ND]
__global__ __launch_bounds__(256) void k_prep(const float* __restrict__ cb,
                                              unsigned short* __restrict__ Bh) {
  int b = blockIdx.x, t = threadIdx.x;
  float4 v = ((const float4*)(cb + (size_t)b * ND))[t];
  ushort4 h;
  h.x = f2bf(v.x); h.y = f2bf(v.y); h.z = f2bf(v.z); h.w = f2bf(v.w);
  ((ushort4*)(Bh + (size_t)b * ND))[t] = h;
}

// Init: residual(f32, in d_out) = targets; Ah = bf16(targets); active flags.
__global__ __launch_bounds__(256) void k_init(const float* __restrict__ tgt,
                                              float* __restrict__ resid,
                                              unsigned short* __restrict__ Ah,
                                              int* __restrict__ active) {
  int b = blockIdx.x, t = threadIdx.x;
  float4 v = ((const float4*)(tgt + (size_t)b * ND))[t];
  ((float4*)(resid + (size_t)b * ND))[t] = v;
  ushort4 h;
  h.x = f2bf(v.x); h.y = f2bf(v.y); h.z = f2bf(v.z); h.w = f2bf(v.w);
  ((ushort4*)(Ah + (size_t)b * ND))[t] = h;
  float ss = v.x * v.x + v.y * v.y + v.z * v.z + v.w * v.w;
  ss = wave_reduce_sum(ss);
  __shared__ float red[4];
  if ((t & 63) == 0) red[t >> 6] = ss;
  __syncthreads();
  if (t == 0) {
    float tot = red[0] + red[1] + red[2] + red[3];
    active[b] = (sqrtf(tot) >= RES_THR) ? 1 : 0;
  }
}

// 256x256-tile bf16 GEMM core (8 waves, BK=64, dbuf LDS, counted vmcnt).
// Writes optional bf16 score tile (sc) and optional per-row top-2 (part).
__global__ __launch_bounds__(512) void k_score0(
    const unsigned short* __restrict__ Ah, const unsigned short* __restrict__ Bh,
    float4* __restrict__ part, unsigned short* __restrict__ sc) {
  __shared__ __align__(16) char sA0[32768];
  __shared__ __align__(16) char sA1[32768];
  __shared__ __align__(16) char sB0[32768];
  __shared__ __align__(16) char sB1[32768];
  const int tid = threadIdx.x;
  const int lane = tid & 63;
  const int swzid = (blockIdx.x & 7) * 64 + (blockIdx.x >> 3);
  const int bm = swzid >> 4;
  const int bn = swzid & 15;
  const int wid = tid >> 6;
  const int wr = wid >> 2;
  const int wc = wid & 3;

  const int srow = tid >> 3;
  const int sblk = (tid & 7) ^ (srow & 7);
  const unsigned short* aSrc = Ah + (size_t)(bm * 256 + srow) * ND + sblk * 8;
  const unsigned short* bSrc = Bh + (size_t)(bn * 256 + srow) * ND + sblk * 8;

  const int lr = lane & 15;
  const int lk = lane >> 4;
  const int swz = lr & 7;
  const int kb0 = ((lk ^ swz) << 4);
  const int kb1 = (((4 + lk) ^ swz) << 4);

  f32x4 acc[8][4];
#pragma unroll
  for (int m = 0; m < 8; ++m)
#pragma unroll
    for (int n = 0; n < 4; ++n) acc[m][n] = (f32x4)(0.f);

#pragma unroll
  for (int rr = 0; rr < 4; ++rr) {
    GLOAD(aSrc + (size_t)(rr * 64) * ND, sA0 + rr * 8192 + tid * 16);
    GLOAD(bSrc + (size_t)(rr * 64) * ND, sB0 + rr * 8192 + tid * 16);
  }
#pragma unroll
  for (int rr = 0; rr < 4; ++rr) {
    GLOAD(aSrc + (size_t)(rr * 64) * ND + 64, sA1 + rr * 8192 + tid * 16);
    GLOAD(bSrc + (size_t)(rr * 64) * ND + 64, sB1 + rr * 8192 + tid * 16);
  }

#pragma unroll 1
  for (int kt = 0; kt < 16; ++kt) {
    const char* pa = (kt & 1) ? sA1 : sA0;
    const char* pb = (kt & 1) ? sB1 : sB0;
    if (kt < 15) {
      asm volatile("s_waitcnt vmcnt(8)" ::: "memory");
    } else {
      asm volatile("s_waitcnt vmcnt(0)" ::: "memory");
    }
    __builtin_amdgcn_s_barrier();
    bf16x8 af0[8], bf0[4];
#pragma unroll
    for (int m = 0; m < 8; ++m)
      af0[m] = *(const bf16x8*)(pa + (wr * 128 + m * 16 + lr) * 128 + kb0);
#pragma unroll
    for (int n = 0; n < 4; ++n)
      bf0[n] = *(const bf16x8*)(pb + (wc * 64 + n * 16 + lr) * 128 + kb0);
    __builtin_amdgcn_s_setprio(1);
#pragma unroll
    for (int m = 0; m < 8; ++m)
#pragma unroll
      for (int n = 0; n < 4; ++n) acc[m][n] = MFMA16(af0[m], bf0[n], acc[m][n]);
    __builtin_amdgcn_s_setprio(0);
    bf16x8 af1[8], bf1[4];
#pragma unroll
    for (int m = 0; m < 8; ++m)
      af1[m] = *(const bf16x8*)(pa + (wr * 128 + m * 16 + lr) * 128 + kb1);
#pragma unroll
    for (int n = 0; n < 4; ++n)
      bf1[n] = *(const bf16x8*)(pb + (wc * 64 + n * 16 + lr) * 128 + kb1);
    __syncthreads();  // all waves done reading buf[kt&1]
    if (kt < 14) {
      const int k0 = (kt + 2) << 6;
      char* da = (kt & 1) ? sA1 : sA0;
      char* db = (kt & 1) ? sB1 : sB0;
#pragma unroll
      for (int rr = 0; rr < 4; ++rr) {
        GLOAD(aSrc + (size_t)(rr * 64) * ND + k0, da + rr * 8192 + tid * 16);
        GLOAD(bSrc + (size_t)(rr * 64) * ND + k0, db + rr * 8192 + tid * 16);
      }
    }
    __builtin_amdgcn_s_setprio(1);
#pragma unroll
    for (int m = 0; m < 8; ++m)
#pragma unroll
      for (int n = 0; n < 4; ++n) acc[m][n] = MFMA16(af1[m], bf1[n], acc[m][n]);
    __builtin_amdgcn_s_setprio(0);
  }
  __syncthreads();

  // optional bf16 scores store
  if (sc) {
#pragma unroll
    for (int m = 0; m < 8; ++m) {
      int row = bm * 256 + wr * 128 + m * 16 + lk * 4;
#pragma unroll
      for (int q = 0; q < 4; ++q)
#pragma unroll
        for (int n = 0; n < 4; ++n)
          sc[(size_t)(row + q) * NK + bn * 256 + wc * 64 + n * 16 + lr] =
              f2bf(acc[m][n][q]);
    }
  }

  // optional fused top-2 per row (fallback path only)
  if (part) {
    float4* red = (float4*)sA0;
#pragma unroll
    for (int m = 0; m < 8; ++m) {
#pragma unroll
      for (int q = 0; q < 4; ++q) {
        float v1 = acc[m][0][q];
        int k1 = bn * 256 + wc * 64 + lr;
        float v2 = -INFINITY;
        int k2 = 0x7fffffff;
#pragma unroll
        for (int n = 1; n < 4; ++n) {
          top2_merge(v1, k1, v2, k2, acc[m][n][q],
                     bn * 256 + wc * 64 + n * 16 + lr, -INFINITY, 0x7fffffff);
        }
#pragma unroll
        for (int msk = 1; msk < 16; msk <<= 1) {
          float ov1 = __shfl_xor(v1, msk);
          int ok1 = __shfl_xor(k1, msk);
          float ov2 = __shfl_xor(v2, msk);
          int ok2 = __shfl_xor(k2, msk);
          top2_merge(v1, k1, v2, k2, ov1, ok1, ov2, ok2);
        }
        if (lr == 0) {
          int row = wr * 128 + m * 16 + lk * 4 + q;
          red[row * 4 + wc] =
              make_float4(v1, __int_as_float(k1), v2, __int_as_float(k2));
        }
      }
    }
    __syncthreads();
    if (tid < 256) {
      float4 e0 = red[tid * 4 + 0];
      float v1 = e0.x; int k1 = __float_as_int(e0.y);
      float v2 = e0.z; int k2 = __float_as_int(e0.w);
#pragma unroll
      for (int j = 1; j < 4; ++j) {
        float4 e = red[tid * 4 + j];
        top2_merge(v1, k1, v2, k2, e.x, __float_as_int(e.y), e.z,
                   __float_as_int(e.w));
      }
      part[(size_t)(bm * 256 + tid) * 16 + bn] =
          make_float4(v1, __int_as_float(k1), v2, __int_as_float(k2));
    }
  }
}

// Gram: G[i][j] = bf16(cb_i) . bf16(cb_j), bf16 out. Same GEMM core, 16x16 grid.
__global__ __launch_bounds__(512) void k_gram(const unsigned short* __restrict__ Bh,
                                              unsigned short* __restrict__ G) {
  __shared__ __align__(16) char sA0[32768];
  __shared__ __align__(16) char sA1[32768];
  __shared__ __align__(16) char sB0[32768];
  __shared__ __align__(16) char sB1[32768];
  const int tid = threadIdx.x;
  const int lane = tid & 63;
  const int bm = blockIdx.x >> 4;
  const int bn = blockIdx.x & 15;
  const int wid = tid >> 6;
  const int wr = wid >> 2;
  const int wc = wid & 3;
  const int srow = tid >> 3;
  const int sblk = (tid & 7) ^ (srow & 7);
  const unsigned short* aSrc = Bh + (size_t)(bm * 256 + srow) * ND + sblk * 8;
  const unsigned short* bSrc = Bh + (size_t)(bn * 256 + srow) * ND + sblk * 8;
  const int lr = lane & 15;
  const int lk = lane >> 4;
  const int swz = lr & 7;
  const int kb0 = ((lk ^ swz) << 4);
  const int kb1 = (((4 + lk) ^ swz) << 4);

  f32x4 acc[8][4];
#pragma unroll
  for (int m = 0; m < 8; ++m)
#pragma unroll
    for (int n = 0; n < 4; ++n) acc[m][n] = (f32x4)(0.f);

#pragma unroll
  for (int rr = 0; rr < 4; ++rr) {
    GLOAD(aSrc + (size_t)(rr * 64) * ND, sA0 + rr * 8192 + tid * 16);
    GLOAD(bSrc + (size_t)(rr * 64) * ND, sB0 + rr * 8192 + tid * 16);
  }
#pragma unroll
  for (int rr = 0; rr < 4; ++rr) {
    GLOAD(aSrc + (size_t)(rr * 64) * ND + 64, sA1 + rr * 8192 + tid * 16);
    GLOAD(bSrc + (size_t)(rr * 64) * ND + 64, sB1 + rr * 8192 + tid * 16);
  }
#pragma unroll 1
  for (int kt = 0; kt < 16; ++kt) {
    const char* pa = (kt & 1) ? sA1 : sA0;
    const char* pb = (kt & 1) ? sB1 : sB0;
    if (kt < 15) {
      asm volatile("s_waitcnt vmcnt(8)" ::: "memory");
    } else {
      asm volatile("s_waitcnt vmcnt(0)" ::: "memory");
    }
    __builtin_amdgcn_s_barrier();
    bf16x8 af0[8], bf0[4];
#pragma unroll
    for (int m = 0; m < 8; ++m)
      af0[m] = *(const bf16x8*)(pa + (wr * 128 + m * 16 + lr) * 128 + kb0);
#pragma unroll
    for (int n = 0; n < 4; ++n)
      bf0[n] = *(const bf16x8*)(pb + (wc * 64 + n * 16 + lr) * 128 + kb0);
    __builtin_amdgcn_s_setprio(1);
#pragma unroll
    for (int m = 0; m < 8; ++m)
#pragma unroll
      for (int n = 0; n < 4; ++n) acc[m][n] = MFMA16(af0[m], bf0[n], acc[m][n]);
    __builtin_amdgcn_s_setprio(0);
    bf16x8 af1[8], bf1[4];
#pragma unroll
    for (int m = 0; m < 8; ++m)
      af1[m] = *(const bf16x8*)(pa + (wr * 128 + m * 16 + lr) * 128 + kb1);
#pragma unroll
    for (int n = 0; n < 4; ++n)
      bf1[n] = *(const bf16x8*)(pb + (wc * 64 + n * 16 + lr) * 128 + kb1);
    __syncthreads();
    if (kt < 14) {
      const int k0 = (kt + 2) << 6;
      char* da = (kt & 1) ? sA1 : sA0;
      char* db = (kt & 1) ? sB1 : sB0;
#pragma unroll
      for (int rr = 0; rr < 4; ++rr) {
        GLOAD(aSrc + (size_t)(rr * 64) * ND + k0, da + rr * 8192 + tid * 16);
        GLOAD(bSrc + (size_t)(rr * 64) * ND + k0, db + rr * 8192 + tid * 16);
      }
    }
    __builtin_amdgcn_s_setprio(1);
#pragma unroll
    for (int m = 0; m < 8; ++m)
#pragma unroll
      for (int n = 0; n < 4; ++n) acc[m][n] = MFMA16(af1[m], bf1[n], acc[m][n]);
    __builtin_amdgcn_s_setprio(0);
  }
#pragma unroll
  for (int m = 0; m < 8; ++m) {
    int row = bm * 256 + wr * 128 + m * 16 + lk * 4;
#pragma unroll
    for (int q = 0; q < 4; ++q)
#pragma unroll
      for (int n = 0; n < 4; ++n)
        G[(size_t)(row + q) * NK + bn * 256 + wc * 64 + n * 16 + lr] =
            f2bf(acc[m][n][q]);
  }
}

// Fused full loop, one block per row. Scores in f32 registers across steps.
// Per step: max -> margin candidates -> cnt==1 fast path (provably exact,
// skips rescore; cb/G update loads issue immediately and in parallel) else
// serial exact rescore -> residual + reg-scores update.
__global__ __launch_bounds__(256) void k_all(
    const unsigned short* __restrict__ sc0, const unsigned short* __restrict__ G,
    const float* __restrict__ cb, float* __restrict__ resid,
    float* __restrict__ out_idx, const int* __restrict__ active0) {
  const int b = blockIdx.x, t = threadIdx.x;
  __shared__ float s_max[4];
  __shared__ float s_nrm[4];
  __shared__ float s_red[4];
  __shared__ int s_cnt;
  __shared__ int s_spec;
  __shared__ int s_k[64];
  __shared__ float s_bv;
  __shared__ int s_bk;

  float4 r = ((const float4*)(resid + (size_t)b * ND))[t];

  float scv[16];
  {
    const unsigned short* srow = sc0 + (size_t)b * NK;
    uint4 v0 = *(const uint4*)(srow + t * 8);
    uint4 v1 = *(const uint4*)(srow + 2048 + t * 8);
    unsigned w[8] = {v0.x, v0.y, v0.z, v0.w, v1.x, v1.y, v1.z, v1.w};
#pragma unroll
    for (int j = 0; j < 8; ++j) {
      scv[2 * j] = bf2f((unsigned short)(w[j] & 0xffff));
      scv[2 * j + 1] = bf2f((unsigned short)(w[j] >> 16));
    }
  }
  int act = active0[b];
  float decay = 1.0f;

#pragma unroll 1
  for (int s = 0; s < NL; ++s) {
    // phase 1: block max of scores + residual norm (fused shuffle reduce)
    float m = scv[0];
#pragma unroll
    for (int i = 1; i < 16; ++i) m = fmaxf(m, scv[i]);
    float ss = r.x * r.x + r.y * r.y + r.z * r.z + r.w * r.w;
#pragma unroll
    for (int off = 32; off > 0; off >>= 1) {
      m = fmaxf(m, __shfl_xor(m, off));
      ss += __shfl_xor(ss, off);
    }
    if ((t & 63) == 0) { s_max[t >> 6] = m; s_nrm[t >> 6] = ss; }
    if (t == 0) {
      s_cnt = 0;
      s_spec = 0x7fffffff;
      s_bv = -INFINITY;
      s_bk = 0x7fffffff;
    }
    __syncthreads();
    const float M = fmaxf(fmaxf(s_max[0], s_max[1]), fmaxf(s_max[2], s_max[3]));
    const float nrm = s_nrm[0] + s_nrm[1] + s_nrm[2] + s_nrm[3];
    act = (act && sqrtf(nrm) >= RES_THR) ? 1 : 0;
    const float margin = (s == 0) ? 2.5f : 6.0f;
    // phase 2: collect candidates within margin; record approx argmax (spec)
#pragma unroll
    for (int i = 0; i < 16; ++i) {
      if (scv[i] >= M - margin) {
        int col = (i < 8) ? (t * 8 + i) : (2048 + t * 8 + (i - 8));
        int pos = atomicAdd(&s_cnt, 1);
        if (pos < 64) s_k[pos] = col;
        if (scv[i] == M) atomicMin(&s_spec, col);
      }
    }
    __syncthreads();
    const int cnt = s_cnt < 64 ? s_cnt : 64;
    int kbest;
    if (cnt <= 1) {
      // sole candidate within margin == true argmax (margin >= 2*err bound).
      // Skip rescore: cb/G update loads below issue with one overlapped
      // latency right after this point.
      kbest = s_spec;
    } else {
      for (int c = 0; c < cnt; ++c) {
        int k = s_k[c];
        float4 cv = ((const float4*)(cb + (size_t)k * ND))[t];
        float dd = r.x * cv.x + r.y * cv.y + r.z * cv.z + r.w * cv.w;
        dd = wave_reduce_sum(dd);
        if ((t & 63) == 0) s_red[t >> 6] = dd;
        __syncthreads();
        if (t == 0) {
          float scr = s_red[0] + s_red[1] + s_red[2] + s_red[3];
          if (scr > s_bv || (scr == s_bv && k < s_bk)) { s_bv = scr; s_bk = k; }
        }
        __syncthreads();
      }
      kbest = s_bk;
    }
    if (t == 0) out_idx[(size_t)b * NL + s] = act ? (float)kbest : -1.0f;
    if (act) {
      float4 cv = ((const float4*)(cb + (size_t)kbest * ND))[t];
      r.x -= decay * cv.x;
      r.y -= decay * cv.y;
      r.z -= decay * cv.z;
      r.w -= decay * cv.w;
      if (s < NL - 1) {
        const unsigned short* grow = G + (size_t)kbest * NK;
        uint4 g0 = *(const uint4*)(grow + t * 8);
        uint4 g1 = *(const uint4*)(grow + 2048 + t * 8);
        unsigned w[8] = {g0.x, g0.y, g0.z, g0.w, g1.x, g1.y, g1.z, g1.w};
#pragma unroll
        for (int j = 0; j < 8; ++j) {
          scv[2 * j] -= decay * bf2f((unsigned short)(w[j] & 0xffff));
          scv[2 * j + 1] -= decay * bf2f((unsigned short)(w[j] >> 16));
        }
      }
    }
    decay *= 0.9f;
    __syncthreads();  // protect s_* resets at top of next step
  }
  ((float4*)(resid + (size_t)b * ND))[t] = r;
}

// Merge partials (fallback path only).
__global__ __launch_bounds__(256) void k_update(
    float* __restrict__ resid, const float* __restrict__ cb,
    const float4* __restrict__ part, int* __restrict__ active,
    float* __restrict__ out_idx, unsigned short* __restrict__ Ah, float decay,
    int s, int nseg, float margin) {
  int b = blockIdx.x, t = threadIdx.x;
  __shared__ int s_cnt;
  __shared__ int s_k[32];
  __shared__ float s_red[4];
  __shared__ float s_bv;
  __shared__ int s_bk;

  float4 r = ((const float4*)(resid + (size_t)b * ND))[t];

  if (t < 2 * nseg) {
    float4 e = part[(size_t)b * 16 + (t >> 1)];
    float v = (t & 1) ? e.z : e.x;
    int k = __float_as_int((t & 1) ? e.w : e.y);
    float M = v;
    for (int off = nseg; off > 0; off >>= 1) M = fmaxf(M, __shfl_xor(M, off));
    bool cand = (v >= M - margin);
    unsigned long long mask = __ballot(cand);
    int slot = __popcll(mask & ((1ull << t) - 1ull));
    if (cand && slot < 32) s_k[slot] = k;
    if (t == 0) {
      int n = (int)__popcll(mask);
      s_cnt = n < 32 ? n : 32;
      s_bv = -INFINITY;
      s_bk = 0x7fffffff;
    }
  }
  __syncthreads();
  int cnt = s_cnt;
  for (int c = 0; c < cnt; ++c) {
    int k = s_k[c];
    float4 cv = ((const float4*)(cb + (size_t)k * ND))[t];
    float dd = r.x * cv.x + r.y * cv.y + r.z * cv.z + r.w * cv.w;
    dd = wave_reduce_sum(dd);
    if ((t & 63) == 0) s_red[t >> 6] = dd;
    __syncthreads();
    if (t == 0) {
      float sc = s_red[0] + s_red[1] + s_red[2] + s_red[3];
      if (sc > s_bv || (sc == s_bv && k < s_bk)) { s_bv = sc; s_bk = k; }
    }
    __syncthreads();
  }
  int kbest = s_bk;
  int act = active[b];
  float4 cv = ((const float4*)(cb + (size_t)kbest * ND))[t];
  if (act) {
    r.x -= decay * cv.x;
    r.y -= decay * cv.y;
    r.z -= decay * cv.z;
    r.w -= decay * cv.w;
  }
  ((float4*)(resid + (size_t)b * ND))[t] = r;
  if (Ah) {
    ushort4 h;
    h.x = f2bf(r.x); h.y = f2bf(r.y); h.z = f2bf(r.z); h.w = f2bf(r.w);
    ((ushort4*)(Ah + (size_t)b * ND))[t] = h;
  }
  float ss = r.x * r.x + r.y * r.y + r.z * r.z + r.w * r.w;
  ss = wave_reduce_sum(ss);
  if ((t & 63) == 0) s_red[t >> 6] = ss;
  __syncthreads();
  if (t == 0) {
    float tot = s_red[0] + s_red[1] + s_red[2] + s_red[3];
    out_idx[(size_t)b * NL + s] = act ? (float)kbest : -1.0f;
    active[b] = (act && sqrtf(tot) >= RES_THR) ? 1 : 0;
  }
}

extern "C" void kernel_launch(void* const* d_in, const int* in_sizes, int n_in,
                              void* d_out, int out_size, void* d_ws,
                              size_t ws_size, hipStream_t stream) {
  const float* targets = (const float*)d_in[0];
  const float* codebook = (const float*)d_in[1];
  float* out = (float*)d_out;
  float* out_idx = out;
  float* resid = out + (size_t)NB * NL;

  char* ws = (char*)d_ws;
  const size_t SC_SZ = (size_t)NB * NK * 2;        // 64MB
  const size_t G_SZ = (size_t)NK * NK * 2;         // 32MB
  const size_t AH_SZ = (size_t)NB * ND * 2;        // 16MB
  const size_t BH_SZ = (size_t)NK * ND * 2;        // 8MB
  const size_t PART_SZ = (size_t)NB * 16 * 16;     // 2MB
  const size_t NEED = SC_SZ + G_SZ + AH_SZ + BH_SZ + PART_SZ + 32768;

  if (ws_size >= NEED) {
    // incremental-Gram path, fully fused step loop
    unsigned short* scores = (unsigned short*)ws;
    unsigned short* G = (unsigned short*)(ws + SC_SZ);
    unsigned short* Ah = (unsigned short*)(ws + SC_SZ + G_SZ);
    unsigned short* Bh = (unsigned short*)(ws + SC_SZ + G_SZ + AH_SZ);
    int* active = (int*)(ws + SC_SZ + G_SZ + AH_SZ + BH_SZ + PART_SZ);

    k_prep<<<NK, 256, 0, stream>>>(codebook, Bh);
    k_init<<<NB, 256, 0, stream>>>(targets, resid, Ah, active);
    k_gram<<<256, 512, 0, stream>>>(Bh, G);
    k_score0<<<(NB / 256) * (NK / 256), 512, 0, stream>>>(Ah, Bh, nullptr,
                                                          scores);
    k_all<<<NB, 256, 0, stream>>>(scores, G, codebook, resid, out_idx, active);
  } else {
    // fallback: proven round-8 loop (full GEMM per step)
    float4* part = (float4*)ws;
    int* active = (int*)(ws + PART_SZ);
    unsigned short* Ah = (unsigned short*)(ws + PART_SZ + 65536);
    unsigned short* Bh = Ah + (size_t)NB * ND;

    k_prep<<<NK, 256, 0, stream>>>(codebook, Bh);
    k_init<<<NB, 256, 0, stream>>>(targets, resid, Ah, active);
    for (int s = 0; s < NL; ++s) {
      k_score0<<<(NB / 256) * (NK / 256), 512, 0, stream>>>(Ah, Bh, part,
                                                            nullptr);
      float ds = (float)pow(0.9, (double)s);
      k_update<<<NB, 256, 0, stream>>>(resid, codebook, part, active, out_idx,
                                       Ah, ds, s, 16, 2.5f);
    }
  }
}